// Round 7
// baseline (313.196 us; speedup 1.0000x reference)
//
#include <hip/hip_runtime.h>
#include <stdint.h>

#define N_TOK 2048
#define C_DIM 1024
#define H_DIM 2048
#define NE 8
#define NSLOT 3

#define BM 128
#define BN 64
#define BK 64
#define PGRID 1024   // persistent GEMM blocks: 256 CU x 4 resident

// ws layout (bytes); every section multiple of 256
#define WS_COUNTS   0
#define WS_PLAN     256
#define WS_CW       (WS_PLAN + 1024)
#define WS_LISTS    (WS_CW + N_TOK*NE*4)
#define WS_XB       (WS_LISTS + NE*N_TOK*4)
#define WS_HBUF     (WS_XB + (size_t)N_TOK*C_DIM*2)
#define WS_OUTSLOT  (WS_HBUF + (size_t)N_TOK*NSLOT*H_DIM*2)
#define WS_WT1T     (WS_OUTSLOT + (size_t)N_TOK*NSLOT*C_DIM*4)
#define WS_WT3T     (WS_WT1T + (size_t)NE*H_DIM*C_DIM*2)
#define WS_WT2T     (WS_WT3T + (size_t)NE*H_DIM*C_DIM*2)
// total ≈ 155 MB

typedef short bf16x8 __attribute__((ext_vector_type(8)));
typedef float f32x4 __attribute__((ext_vector_type(4)));

union FragU { bf16x8 v; uint2 u2[2]; };

__device__ __forceinline__ unsigned short f2b(float f) {
    union { float f; uint32_t u; } v; v.f = f;
    return (unsigned short)((v.u + 0x7fffu + ((v.u >> 16) & 1u)) >> 16); // RNE
}

// async global->LDS, 16B per lane; lds dest is wave-uniform base + lane*16
__device__ __forceinline__ void gload16(const unsigned short* g, unsigned short* l) {
    __builtin_amdgcn_global_load_lds(
        (const __attribute__((address_space(1))) unsigned int*)g,
        (__attribute__((address_space(3))) unsigned int*)l, 16, 0, 0);
}

__global__ void zero_kernel(int* counts) {
    if (threadIdx.x < NE) counts[threadIdx.x] = 0;
}

// ---- tcast v3: 64k x 256n fp32 -> 8 output tiles of [32 n-rows][64 k] bf16 (4KB each)
// Tiles are the GEMM's staging unit: dst tile (rb, kt) at dtile0 + s2*NKT*2048.
// Phase 1: coalesced 1KB row reads, pack k-pairs, ds_write_b32 into pitch-132B
//   LDS (bank = (lane+pair) mod 32 -> 32 banks, 2 lanes each: conflict-free).
// Phase 2: 4x b32 LDS reads (~2/bank), uint4 global stores, 1KB/wave contiguous.
__device__ __forceinline__ void tcast256(
        const float* __restrict__ src, unsigned short* __restrict__ dtile0,
        int N, int NKT, int kt, int nBase, char* lb, int t) {
    const int l = t & 63, w = t >> 6;
    const float* s = src + (size_t)(kt * 64) * N + nBase;
#pragma unroll 2
    for (int i = 0; i < 8; i++) {
        int p = w + 4 * i;                       // k-pair index 0..31
        const float* r0 = s + (size_t)(2 * p) * N;
        const float* r1 = r0 + N;
#pragma unroll
        for (int q = 0; q < 4; q++) {
            float lo = r0[q * 64 + l];
            float hi = r1[q * 64 + l];
            uint32_t pk = (uint32_t)f2b(lo) | ((uint32_t)f2b(hi) << 16);
            *(uint32_t*)(lb + (q * 64 + l) * 132 + p * 4) = pk;
        }
    }
    __syncthreads();
    const int rn = t >> 3, cc = t & 7;
#pragma unroll
    for (int s2 = 0; s2 < 8; s2++) {
        int nrow = s2 * 32 + rn;
        uint32_t w0 = *(const uint32_t*)(lb + nrow * 132 + cc * 16 + 0);
        uint32_t w1_ = *(const uint32_t*)(lb + nrow * 132 + cc * 16 + 4);
        uint32_t w2_ = *(const uint32_t*)(lb + nrow * 132 + cc * 16 + 8);
        uint32_t w3_ = *(const uint32_t*)(lb + nrow * 132 + cc * 16 + 12);
        uint4 v = {w0, w1_, w2_, w3_};
        unsigned short* drow = dtile0 + (size_t)s2 * NKT * 2048 + rn * 64 + cc * 8;
        *(uint4*)drow = v;
    }
}

// ---------------- fused gate (blocks 0..511) + w1/w3 tcast (512..2559) ----------------
__global__ __launch_bounds__(256) void gate_tcast_kernel(
        const float* __restrict__ x, const float* __restrict__ gw,
        const float* __restrict__ gb, const float* __restrict__ w1,
        const float* __restrict__ w3, float* __restrict__ cw,
        unsigned short* __restrict__ xb, int* __restrict__ counts,
        int* __restrict__ lists, unsigned short* __restrict__ wt1t,
        unsigned short* __restrict__ wt3t) {
    __shared__ __align__(16) char smem[33792];
    if (blockIdx.x >= 512) {
        int bb = blockIdx.x - 512;
        int op = bb >> 10, r2 = bb & 1023;
        int e = r2 >> 7, rem = r2 & 127, kt = rem >> 3, nB = rem & 7;
        const float* src = (op ? w3 : w1) + (size_t)e * C_DIM * H_DIM;
        unsigned short* dst = (op ? wt3t : wt1t) +
                              ((size_t)(e * 64 + nB * 8) * 16 + kt) * 2048;
        tcast256(src, dst, H_DIM, 16, kt, nB * 256, smem, threadIdx.x);
        return;
    }
    int n = (blockIdx.x * 256 + threadIdx.x) >> 6;
    int lane = threadIdx.x & 63;
    float acc[NE];
#pragma unroll
    for (int e = 0; e < NE; e++) acc[e] = 0.f;
    for (int c = lane; c < C_DIM; c += 64) {
        float xv = x[n * C_DIM + c];
        xb[n * C_DIM + c] = f2b(xv);
        const float* g = gw + c * NE;
#pragma unroll
        for (int e = 0; e < NE; e++) acc[e] += xv * g[e];
    }
#pragma unroll
    for (int e = 0; e < NE; e++) {
#pragma unroll
        for (int off = 32; off >= 1; off >>= 1) acc[e] += __shfl_xor(acc[e], off, 64);
        acc[e] += gb[e];
    }
    float m = acc[0];
#pragma unroll
    for (int e = 1; e < NE; e++) m = fmaxf(m, acc[e]);
    float s = 0.f, sc[NE];
#pragma unroll
    for (int e = 0; e < NE; e++) { sc[e] = __expf(acc[e] - m); s += sc[e]; }
    float inv = 1.f / s;
#pragma unroll
    for (int e = 0; e < NE; e++) sc[e] *= inv;
    // top-2 of routed experts 1..7; ties -> lower index (matches lax.top_k)
    int i1 = 1; float v1 = sc[1];
#pragma unroll
    for (int e = 2; e < NE; e++) if (sc[e] > v1) { v1 = sc[e]; i1 = e; }
    int i2 = 0; float v2 = -1.f;
#pragma unroll
    for (int e = 1; e < NE; e++) if (e != i1 && sc[e] > v2) { v2 = sc[e]; i2 = e; }
    if (lane < NE) {
        float v = 0.f;
        if (lane == 0) v = sc[0];
        else if (lane == i1) v = v1;
        else if (lane == i2) v = v2;
        cw[n * NE + lane] = v;
    }
    if (lane == 0) {  // entry = token*4 + slot
        int p0 = atomicAdd(&counts[0], 1);  lists[p0] = n * 4 + 0;
        int p1 = atomicAdd(&counts[i1], 1); lists[i1 * N_TOK + p1] = n * 4 + 1;
        int p2 = atomicAdd(&counts[i2], 1); lists[i2 * N_TOK + p2] = n * 4 + 2;
    }
}

// ---------------- plan: compacted (expert, m-block) work list ----------------
__global__ void plan_kernel(const int* __restrict__ counts, int* __restrict__ plan) {
    if (threadIdx.x == 0) {
        int p = 0;
        for (int e = 0; e < NE; e++) {
            int nb = (counts[e] + BM - 1) / BM;
            for (int m = 0; m < nb; m++) plan[1 + p++] = (e << 8) | m;
        }
        plan[0] = p;
    }
}

// STAGE: 4 A-chunks + 2 B-chunks per lane (async 16B global->LDS)
#define STAGE(aoff, boff) do {                                            \
    _Pragma("unroll")                                                     \
    for (int i_ = 0; i_ < 4; i_++)                                        \
        gload16(asrc[i_] + (aoff), As + (i_ * 256 + t) * 8);              \
    _Pragma("unroll")                                                     \
    for (int i_ = 0; i_ < 2; i_++)                                        \
        gload16(bsrc[i_] + (boff), Bs + (i_ * 256 + t) * 8);              \
} while (0)

// COMPUTE: 12 ds_read_b128 + 16 MFMA on one 128x64x64 tile (wave tile 64x32)
// BEXPR: B LDS row as an expression of nt (differs up vs down)
#define COMPUTE(BEXPR) do {                                               \
    __builtin_amdgcn_s_setprio(1);                                        \
    _Pragma("unroll")                                                     \
    for (int j_ = 0; j_ < 2; j_++) {                                      \
        FragU af[4], bf[2];                                               \
        _Pragma("unroll")                                                 \
        for (int mt = 0; mt < 4; mt++) {                                  \
            int row = wr * 64 + mt * 16 + ln15;                           \
            int slot = (j_ * 4 + lg) ^ swz;                               \
            af[mt].v = *(const bf16x8*)(As + row * BK + slot * 8);        \
        }                                                                 \
        _Pragma("unroll")                                                 \
        for (int nt = 0; nt < 2; nt++) {                                  \
            int row = (BEXPR);                                            \
            int slot = (j_ * 4 + lg) ^ swz;                               \
            bf[nt].v = *(const bf16x8*)(Bs + row * BK + slot * 8);        \
        }                                                                 \
        _Pragma("unroll")                                                 \
        for (int mt = 0; mt < 4; mt++)                                    \
            _Pragma("unroll")                                             \
            for (int nt = 0; nt < 2; nt++)                                \
                acc[mt][nt] = __builtin_amdgcn_mfma_f32_16x16x32_bf16(    \
                    af[mt].v, bf[nt].v, acc[mt][nt], 0, 0, 0);            \
    }                                                                     \
    __builtin_amdgcn_s_setprio(0);                                        \
} while (0)

// single-buffer K-loop: latency hiding via 4 blocks/CU TLP (m114 mechanism)
#define KLOOP(NK, BEXPR) do {                                             \
    for (int kt = 0; kt < (NK); kt++) {                                   \
        STAGE(kt * BK, kt * 2048);                                        \
        asm volatile("s_waitcnt vmcnt(0)" ::: "memory");                  \
        __builtin_amdgcn_s_barrier();                                     \
        COMPUTE(BEXPR);                                                   \
        __builtin_amdgcn_s_barrier();                                     \
    }                                                                     \
} while (0)

// -------- persistent expert up (even blocks) + w2 tcast (odd blocks) --------
// B-tile rows 0-31 = w1t[h0..h0+31], rows 32-63 = w3t[h0..h0+31]; h0 = nb*32.
__global__ __launch_bounds__(256, 4) void expert_up_kernel(
        const unsigned short* __restrict__ xb, const unsigned short* __restrict__ wt1t,
        const unsigned short* __restrict__ wt3t, const float* __restrict__ b1,
        const float* __restrict__ b3, const int* __restrict__ counts,
        const int* __restrict__ lists, const int* __restrict__ plan,
        unsigned short* __restrict__ hbuf, const float* __restrict__ w2,
        unsigned short* __restrict__ wt2t) {
    const int t = threadIdx.x;
    __shared__ __align__(16) char smem[33792];
    unsigned short* As = (unsigned short*)smem;            // 16 KB
    unsigned short* Bs = (unsigned short*)(smem + 16384);  // 8 KB
    int* rowtok = (int*)(smem + 16384 + 8192);             // 512 B

    if (blockIdx.x & 1) {  // w2 -> wt2t tiles, co-dispatched with GEMM blocks
        int bb = blockIdx.x >> 1;
        int e = bb >> 7, rem = bb & 127, kt = rem >> 2, nB2 = rem & 3;
        tcast256(w2 + (size_t)e * H_DIM * C_DIM,
                 wt2t + ((size_t)(e * 32 + nB2 * 8) * 32 + kt) * 2048,
                 C_DIM, 32, kt, nB2 * 256, smem, t);
        return;
    }
    const int bid = blockIdx.x >> 1;       // 0..PGRID-1 persistent
    const int lane = t & 63, w = t >> 6;
    const int ln15 = lane & 15, lg = lane >> 4;
    const int wr = w >> 1, wc = w & 1;
    const int swz = ln15 & 7;

    const int ntile = plan[0] << 6;   // nmb * 64 n-blocks (each 32 h)
    for (int tile = bid; tile < ntile; tile += PGRID) {
        const int mi = tile >> 6, nb = tile & 63;
        const int ent = plan[1 + mi];
        const int e = ent >> 8, m0 = (ent & 255) * BM;
        const int cnt = counts[e];

        if (t < BM) {
            int r = m0 + t;  // tail rows duplicate last valid token (benign)
            rowtok[t] = lists[e * N_TOK + (r < cnt ? r : cnt - 1)];
        }
        __syncthreads();

        const unsigned short* wb1 = wt1t + (size_t)(e * 64 + nb) * 16 * 2048;
        const unsigned short* wb3 = wt3t + (size_t)(e * 64 + nb) * 16 * 2048;
        const unsigned short* asrc[4];
        const unsigned short* bsrc[2];
#pragma unroll
        for (int i = 0; i < 4; i++) {   // A chunk c: row=c>>3, holds kc=(c&7)^(row&7)
            int c = i * 256 + t;
            int row = c >> 3, kc = (c & 7) ^ (row & 7);
            asrc[i] = xb + (size_t)(rowtok[row] >> 2) * C_DIM + kc * 8;
        }
#pragma unroll
        for (int i = 0; i < 2; i++) {
            int c = i * 256 + t;
            int row = c >> 3, kc = (c & 7) ^ (row & 7);
            bsrc[i] = (row < 32 ? wb1 : wb3) + (size_t)(row & 31) * 64 + kc * 8;
        }

        f32x4 acc[4][2];
#pragma unroll
        for (int a = 0; a < 4; a++)
#pragma unroll
            for (int b = 0; b < 2; b++) acc[a][b] = (f32x4){0.f, 0.f, 0.f, 0.f};

        KLOOP(C_DIM / BK, nt * 32 + wc * 16 + ln15);

        // epilogue: nt0 = w1 (a), nt1 = w3 (g), same h per lane
        {
            int h = nb * 32 + wc * 16 + ln15;
            float bb1 = b1[e * H_DIM + h], bb3 = b3[e * H_DIM + h];
#pragma unroll
            for (int mt = 0; mt < 4; mt++) {
#pragma unroll
                for (int jj = 0; jj < 4; jj++) {
                    int mrow = wr * 64 + mt * 16 + lg * 4 + jj;  // C/D row=(lane>>4)*4+reg
                    float av = acc[mt][0][jj] + bb1;
                    float gv = acc[mt][1][jj] + bb3;
                    float hv = av * gv / (1.f + __expf(-gv));    // silu(g)*a
                    int ent2 = rowtok[mrow];
                    hbuf[(size_t)((ent2 >> 2) * NSLOT + (ent2 & 3)) * H_DIM + h] = f2b(hv);
                }
            }
        }
        __syncthreads();   // protect rowtok/LDS before next tile
    }
}

// -------- persistent expert down: [h rows] x [w2t tiles], K = H --------
__global__ __launch_bounds__(256, 4) void expert_down_kernel(
        const unsigned short* __restrict__ hbuf, const unsigned short* __restrict__ wt2t,
        const float* __restrict__ b2, const float* __restrict__ cw,
        const int* __restrict__ counts, const int* __restrict__ lists,
        const int* __restrict__ plan, float* __restrict__ outslot) {
    const int t = threadIdx.x;
    const int lane = t & 63, w = t >> 6;
    const int ln15 = lane & 15, lg = lane >> 4;
    const int wr = w >> 1, wc = w & 1;
    const int swz = ln15 & 7;

    __shared__ __align__(16) char smem[25088];
    unsigned short* As = (unsigned short*)smem;
    unsigned short* Bs = (unsigned short*)(smem + 16384);
    int* rowtok = (int*)(smem + 16384 + 8192);

    const int ntile = plan[0] << 4;   // nmb * 16 c-blocks (N = C = 1024)
    for (int tile = blockIdx.x; tile < ntile; tile += PGRID) {
        const int mi = tile >> 4, nb = tile & 15;
        const int ent = plan[1 + mi];
        const int e = ent >> 8, m0 = (ent & 255) * BM;
        const int cnt = counts[e];
        const int c0 = nb * BN;

        if (t < BM) {
            int r = m0 + t;
            rowtok[t] = lists[e * N_TOK + (r < cnt ? r : cnt - 1)];
        }
        __syncthreads();

        const unsigned short* asrc[4];
        const unsigned short* bsrc[2];
#pragma unroll
        for (int i = 0; i < 4; i++) {
            int c = i * 256 + t;
            int row = c >> 3, kc = (c & 7) ^ (row & 7);
            int ent2 = rowtok[row];
            asrc[i] = hbuf + (size_t)((ent2 >> 2) * NSLOT + (ent2 & 3)) * H_DIM + kc * 8;
        }
#pragma unroll
        for (int i = 0; i < 2; i++) {
            int c = i * 256 + t;
            int row = c >> 3, kc = (c & 7) ^ (row & 7);
            bsrc[i] = wt2t + (size_t)(e * 32 + nb * 2 + (row >> 5)) * 32 * 2048 +
                      (size_t)(row & 31) * 64 + kc * 8;
        }

        f32x4 acc[4][2];
#pragma unroll
        for (int a = 0; a < 4; a++)
#pragma unroll
            for (int b = 0; b < 2; b++) acc[a][b] = (f32x4){0.f, 0.f, 0.f, 0.f};

        KLOOP(H_DIM / BK, wc * 32 + nt * 16 + ln15);

#pragma unroll
        for (int nt = 0; nt < 2; nt++) {
            int col = c0 + wc * 32 + nt * 16 + ln15;
            float bb = b2[e * C_DIM + col];
#pragma unroll
            for (int mt = 0; mt < 4; mt++) {
#pragma unroll
                for (int jj = 0; jj < 4; jj++) {
                    int mrow = wr * 64 + mt * 16 + lg * 4 + jj;
                    int ent2 = rowtok[mrow];
                    int tok = ent2 >> 2, slot = ent2 & 3;
                    float cwv = cw[tok * NE + e];
                    outslot[(size_t)(tok * NSLOT + slot) * C_DIM + col] =
                        cwv * (acc[mt][nt][jj] + bb);
                }
            }
        }
        __syncthreads();
    }
}

// -------- fused reduce (blocks 0..2047) + balance loss (block 2048) --------
__global__ __launch_bounds__(256) void reduce_loss_kernel(
        const float* __restrict__ os, const float* __restrict__ cw,
        const int* __restrict__ counts, float* __restrict__ out) {
    if (blockIdx.x < 2048) {
        int i = blockIdx.x * 256 + threadIdx.x;   // over N*C/4
        int n = i >> 8;
        int c = (i & 255) * 4;
        const float4 s0 = *(const float4*)(os + ((size_t)n * NSLOT + 0) * C_DIM + c);
        const float4 s1 = *(const float4*)(os + ((size_t)n * NSLOT + 1) * C_DIM + c);
        const float4 s2 = *(const float4*)(os + ((size_t)n * NSLOT + 2) * C_DIM + c);
        float4 r;
        r.x = s0.x + s1.x + s2.x; r.y = s0.y + s1.y + s2.y;
        r.z = s0.z + s1.z + s2.z; r.w = s0.w + s1.w + s2.w;
        *(float4*)(out + (size_t)n * C_DIM + c) = r;
    } else if (threadIdx.x < 64) {
        int lane = threadIdx.x;
        float ss[NE];
#pragma unroll
        for (int e = 0; e < NE; e++) ss[e] = 0.f;
        for (int n = lane; n < N_TOK; n += 64) {
#pragma unroll
            for (int e = 0; e < NE; e++) ss[e] += cw[n * NE + e];
        }
#pragma unroll
        for (int e = 0; e < NE; e++) {
#pragma unroll
            for (int off = 32; off >= 1; off >>= 1) ss[e] += __shfl_xor(ss[e], off, 64);
        }
        if (lane == 0) {
            float bal = 0.f;
            const float fac = (float)NE / (3.f * (float)N_TOK * (float)N_TOK);
#pragma unroll
            for (int e = 0; e < NE; e++) bal += fac * (float)counts[e] * ss[e];
            out[(size_t)N_TOK * C_DIM] = bal;
        }
    }
}

extern "C" void kernel_launch(void* const* d_in, const int* in_sizes, int n_in,
                              void* d_out, int out_size, void* d_ws, size_t ws_size,
                              hipStream_t stream) {
    const float* x  = (const float*)d_in[0];
    const float* gw = (const float*)d_in[1];
    const float* gb = (const float*)d_in[2];
    const float* w1 = (const float*)d_in[3];
    const float* b1 = (const float*)d_in[4];
    const float* w2 = (const float*)d_in[5];
    const float* b2 = (const float*)d_in[6];
    const float* w3 = (const float*)d_in[7];
    const float* b3 = (const float*)d_in[8];
    float* out = (float*)d_out;
    char* ws = (char*)d_ws;
    int*            counts = (int*)(ws + WS_COUNTS);
    int*            plan   = (int*)(ws + WS_PLAN);
    float*          cw     = (float*)(ws + WS_CW);
    int*            lists  = (int*)(ws + WS_LISTS);
    unsigned short* xb     = (unsigned short*)(ws + WS_XB);
    unsigned short* hbuf   = (unsigned short*)(ws + WS_HBUF);
    float*          oslot  = (float*)(ws + WS_OUTSLOT);
    unsigned short* wt1t   = (unsigned short*)(ws + WS_WT1T);
    unsigned short* wt3t   = (unsigned short*)(ws + WS_WT3T);
    unsigned short* wt2t   = (unsigned short*)(ws + WS_WT2T);

    hipLaunchKernelGGL(zero_kernel, dim3(1), dim3(64), 0, stream, counts);
    hipLaunchKernelGGL(gate_tcast_kernel, dim3(512 + 2048), dim3(256), 0, stream,
                       x, gw, gb, w1, w3, cw, xb, counts, lists, wt1t, wt3t);
    hipLaunchKernelGGL(plan_kernel, dim3(1), dim3(64), 0, stream, counts, plan);
    hipLaunchKernelGGL(expert_up_kernel, dim3(2 * PGRID), dim3(256), 0, stream,
                       xb, wt1t, wt3t, b1, b3, counts, lists, plan, hbuf, w2, wt2t);
    hipLaunchKernelGGL(expert_down_kernel, dim3(PGRID), dim3(256), 0, stream,
                       hbuf, wt2t, b2, cw, counts, lists, plan, oslot);
    hipLaunchKernelGGL(reduce_loss_kernel, dim3(2049), dim3(256), 0, stream,
                       oslot, cw, counts, out);
}